// Round 1
// baseline (227.968 us; speedup 1.0000x reference)
//
#include <hip/hip_runtime.h>
#include <math.h>

#define LOG2PI_F   1.8378770664093453f
#define LOGPI_F    1.1447298858494002f
#define LOG2_F     0.6931471805599453f
#define ERF3OS2    0.9973002039367398f   // erf(3/sqrt(2)), wf = 3.0 (compile-time)
#define WF         3.0f
#define NMC        1024
#define LOGN_F     6.9314718055994531f   // log(1024)
#define LOGGAMMA15 (-0.12078223763524522f) // log(Gamma(1.5))

// ---------------- Kernel A: per-n tables + header + zero output ----------------
// tab[c][n] = (tx, G, B) with B = -log G + lptx + log(I_diff) - log N + lw[3+c]
__global__ void precompute_kernel(const float* __restrict__ ku12,
                                  const float* __restrict__ ku23,
                                  const float* __restrict__ ku13,
                                  const float* __restrict__ sbp,
                                  const float* __restrict__ snp,
                                  const float* __restrict__ I1p,
                                  const float* __restrict__ I2p,
                                  const float* __restrict__ I3p,
                                  const float* __restrict__ w,
                                  float4* __restrict__ tab,
                                  float* __restrict__ hdr,
                                  float* __restrict__ out) {
    const int n = threadIdx.x;           // 1024 threads, 1 block
    const float sigma_b = sbp[0], sigma_n = snp[0];
    const float I1 = I1p[0], I2 = I2p[0], I3 = I3p[0];
    const float inv_sn2 = 1.0f / (sigma_n * sigma_n);

    // softmax(log-weights): lw = w - logsumexp(w)
    float wv[6];
    #pragma unroll
    for (int i = 0; i < 6; ++i) wv[i] = w[i];
    float wm = wv[0];
    #pragma unroll
    for (int i = 1; i < 6; ++i) wm = fmaxf(wm, wv[i]);
    float wsum = 0.f;
    #pragma unroll
    for (int i = 0; i < 6; ++i) wsum += __expf(wv[i] - wm);
    const float lsew = wm + __logf(wsum);

    const float* kus[3] = {ku12, ku23, ku13};
    const float Ias[3] = {I1, I2, I1};
    const float Ibs[3] = {I2, I3, I3};
    const float gb = rsqrtf(2.0f * (float)M_PI * sigma_b * sigma_b);

    #pragma unroll
    for (int c = 0; c < 3; ++c) {
        const float Ia = Ias[c], Ib = Ibs[c];
        const float gap = Ib - Ia;
        const float I_min  = Ia + 0.5f * gap * (1.0f - ERF3OS2);
        const float I_diff = gap * ERF3OS2;
        const float add_c  = __logf(I_diff) - LOGN_F + (wv[3 + c] - lsew);
        const float ku = kus[c][n];
        const float tx = ku * I_diff + I_min;
        const float v  = 2.0f * (tx - Ia) / gap - 1.0f;
        const float ei = erfinvf(v);
        const float ei2 = ei * ei;
        const float G   = gap * gb * __expf(-ei2);
        const float lptx = -__logf(2.0f * WF * gap) + 0.5f * LOG2PI_F + ei2;
        const float B = -__logf(G) + lptx + add_c;
        tab[c * NMC + n] = make_float4(tx, G, B, 0.f);
    }

    if (n == 0) {
        const float lsn = __logf(sigma_n);
        hdr[0] = inv_sn2;
        hdr[1] = -2.f * lsn - 0.5f * LOG2PI_F - 0.5f * LOGPI_F;        // C_A (A_m = C_A + log y)
        hdr[2] = LOG2_F - LOGGAMMA15 - 4.f * lsn - 0.5f * LOG2PI_F;    // K_int
        hdr[3] = I1; hdr[4] = I2; hdr[5] = I3;
        hdr[6] = wv[0] - lsew; hdr[7] = wv[1] - lsew; hdr[8] = wv[2] - lsew;
        out[0] = 0.f;
    }
}

// ---------------- Kernel B: main loop ----------------
// Block = 256 threads = 4 waves. Lane (0..63) -> data point m; wave -> n-chunk of 256.
#define CHUNK 256

__global__ __launch_bounds__(256) void
main_kernel(const float* __restrict__ xg, const float* __restrict__ yg,
            const float4* __restrict__ tab, const float* __restrict__ hdr,
            float* __restrict__ out, int M) {
    const int lane = threadIdx.x & 63;
    const int wave = threadIdx.x >> 6;
    const int m = blockIdx.x * 64 + lane;
    const bool valid = (m < M);
    const float x = valid ? xg[m] : 0.5f;
    const float y = valid ? yg[m] : 0.5f;

    const float inv_sn2 = hdr[0];
    const float c2 = -4.0f * y * inv_sn2;    // u = exp(-2z) = exp(c2 * G), z = 2 y G / sn^2

    float mx0 = -1e30f, mx1 = -1e30f, mx2 = -1e30f;
    float ac0 = 0.f,   ac1 = 0.f,   ac2 = 0.f;

    const int n0 = wave * CHUNK;
    #pragma unroll 4
    for (int i = 0; i < CHUNK; ++i) {
        const int n = n0 + i;
        {   // comp 0
            const float4 t = tab[0 * NMC + n];
            const float dx = x - t.x, dy = y - t.y;
            const float q = fmaf(0.5f * dx, dx, dy * dy);
            const float s = fmaf(-q, inv_sn2, t.z);
            const float u = __expf(c2 * t.y);
            const float d = s - mx0;
            if (d > 60.0f) { ac0 = fmaf(ac0, __expf(mx0 - s), 1.0f - u); mx0 = s; }
            else           { ac0 = fmaf(__expf(d), 1.0f - u, ac0); }
        }
        {   // comp 1
            const float4 t = tab[1 * NMC + n];
            const float dx = x - t.x, dy = y - t.y;
            const float q = fmaf(0.5f * dx, dx, dy * dy);
            const float s = fmaf(-q, inv_sn2, t.z);
            const float u = __expf(c2 * t.y);
            const float d = s - mx1;
            if (d > 60.0f) { ac1 = fmaf(ac1, __expf(mx1 - s), 1.0f - u); mx1 = s; }
            else           { ac1 = fmaf(__expf(d), 1.0f - u, ac1); }
        }
        {   // comp 2
            const float4 t = tab[2 * NMC + n];
            const float dx = x - t.x, dy = y - t.y;
            const float q = fmaf(0.5f * dx, dx, dy * dy);
            const float s = fmaf(-q, inv_sn2, t.z);
            const float u = __expf(c2 * t.y);
            const float d = s - mx2;
            if (d > 60.0f) { ac2 = fmaf(ac2, __expf(mx2 - s), 1.0f - u); mx2 = s; }
            else           { ac2 = fmaf(__expf(d), 1.0f - u, ac2); }
        }
    }

    __shared__ float pmx[4][3][64];
    __shared__ float pac[4][3][64];
    pmx[wave][0][lane] = mx0; pac[wave][0][lane] = ac0;
    pmx[wave][1][lane] = mx1; pac[wave][1][lane] = ac1;
    pmx[wave][2][lane] = mx2; pac[wave][2][lane] = ac2;
    __syncthreads();

    if (wave == 0) {
        const float ly = __logf(y);
        const float A_m = hdr[1] + ly;
        const float base_int = hdr[2] + 2.f * ly - y * y * inv_sn2;
        float vals[6];
        #pragma unroll
        for (int c = 0; c < 3; ++c) {
            const float dxi = x - hdr[3 + c];
            vals[c] = hdr[6 + c] + base_int - 0.5f * dxi * dxi * inv_sn2;
        }
        #pragma unroll
        for (int c = 0; c < 3; ++c) {
            const float M0 = pmx[0][c][lane], M1 = pmx[1][c][lane];
            const float M2 = pmx[2][c][lane], M3 = pmx[3][c][lane];
            const float MM = fmaxf(fmaxf(M0, M1), fmaxf(M2, M3));
            const float a = pac[0][c][lane] * __expf(M0 - MM)
                          + pac[1][c][lane] * __expf(M1 - MM)
                          + pac[2][c][lane] * __expf(M2 - MM)
                          + pac[3][c][lane] * __expf(M3 - MM);
            vals[3 + c] = A_m + MM + __logf(a);
        }
        float mm = vals[0];
        #pragma unroll
        for (int i = 1; i < 6; ++i) mm = fmaxf(mm, vals[i]);
        float se = 0.f;
        #pragma unroll
        for (int i = 0; i < 6; ++i) se += __expf(vals[i] - mm);
        const float log_mix = mm + __logf(se);
        float contrib = valid ? -log_mix : 0.f;
        #pragma unroll
        for (int off = 32; off > 0; off >>= 1) contrib += __shfl_down(contrib, off);
        if (lane == 0) atomicAdd(out, contrib);
    }
}

extern "C" void kernel_launch(void* const* d_in, const int* in_sizes, int n_in,
                              void* d_out, int out_size, void* d_ws, size_t ws_size,
                              hipStream_t stream) {
    const float* x    = (const float*)d_in[0];
    const float* y    = (const float*)d_in[1];
    const float* ku12 = (const float*)d_in[2];
    const float* ku23 = (const float*)d_in[3];
    const float* ku13 = (const float*)d_in[4];
    const float* sb   = (const float*)d_in[5];
    const float* sn   = (const float*)d_in[6];
    const float* I1   = (const float*)d_in[7];
    const float* I2   = (const float*)d_in[8];
    const float* I3   = (const float*)d_in[9];
    const float* w    = (const float*)d_in[10];
    const int M = in_sizes[0];

    float4* tab = (float4*)d_ws;
    float*  hdr = (float*)((char*)d_ws + 3 * NMC * sizeof(float4));
    float*  out = (float*)d_out;

    precompute_kernel<<<1, NMC, 0, stream>>>(ku12, ku23, ku13, sb, sn, I1, I2, I3, w,
                                             tab, hdr, out);
    const int blocks = (M + 63) / 64;
    main_kernel<<<blocks, 256, 0, stream>>>(x, y, tab, hdr, out, M);
}

// Round 2
// 105.312 us; speedup vs baseline: 2.1647x; 2.1647x over previous
//
#include <hip/hip_runtime.h>
#include <math.h>

#define LOG2PI_F   1.8378770664093453f
#define LOGPI_F    1.1447298858494002f
#define LOG2_F     0.6931471805599453f
#define L2E_F      1.4426950408889634f
#define ERF3OS2    0.9973002039367398f   // erf(3/sqrt(2)), wf = 3.0 (compile-time)
#define WF         3.0f
#define NMC        1024
#define LOGN_F     6.9314718055994531f   // log(1024)
#define LOGGAMMA15 (-0.12078223763524522f) // log(Gamma(1.5))

#if defined(__has_builtin)
#if __has_builtin(__builtin_amdgcn_exp2f)
#define EXP2(v) __builtin_amdgcn_exp2f(v)
#else
#define EXP2(v) __expf((v) * LOG2_F)
#endif
#else
#define EXP2(v) __expf((v) * LOG2_F)
#endif

// ---------------- Kernel A: per-n tables + header + zero output ----------------
// tab[c][n] = (txc, gc, zc) pre-scaled by log2(e):
//   txc = inv_sn2 * tx * L2E          (coefficient of x)
//   gc  = 2 * inv_sn2 * G * L2E       (coefficient of y; also p for the Bessel shift)
//   zc  = (B - 0.5*inv_sn2*tx^2 - inv_sn2*G^2) * L2E
// with B = -log G + lptx + log(I_diff) - log N + lw[3+c]  (validated in round 1).
// Then s*log2e  = Cm + x*txc + y*gc + zc   (Cm = -(0.5x^2+y^2)*inv_sn2*L2E per-m)
//      s2*log2e = s*log2e - 2*y*gc/... = (zc + x*txc + Cm) - y*gc
// term = 2^(b+p) - 2^(b-p),  b = zc + x*txc + Cm, p = y*gc.
__global__ void precompute_kernel(const float* __restrict__ ku12,
                                  const float* __restrict__ ku23,
                                  const float* __restrict__ ku13,
                                  const float* __restrict__ sbp,
                                  const float* __restrict__ snp,
                                  const float* __restrict__ I1p,
                                  const float* __restrict__ I2p,
                                  const float* __restrict__ I3p,
                                  const float* __restrict__ w,
                                  float4* __restrict__ tab,
                                  float* __restrict__ hdr,
                                  float* __restrict__ out) {
    const int n = threadIdx.x;           // 1024 threads, 1 block
    const float sigma_b = sbp[0], sigma_n = snp[0];
    const float I1 = I1p[0], I2 = I2p[0], I3 = I3p[0];
    const float inv_sn2 = 1.0f / (sigma_n * sigma_n);

    // softmax(log-weights): lw = w - logsumexp(w)
    float wv[6];
    #pragma unroll
    for (int i = 0; i < 6; ++i) wv[i] = w[i];
    float wm = wv[0];
    #pragma unroll
    for (int i = 1; i < 6; ++i) wm = fmaxf(wm, wv[i]);
    float wsum = 0.f;
    #pragma unroll
    for (int i = 0; i < 6; ++i) wsum += __expf(wv[i] - wm);
    const float lsew = wm + __logf(wsum);

    const float* kus[3] = {ku12, ku23, ku13};
    const float Ias[3] = {I1, I2, I1};
    const float Ibs[3] = {I2, I3, I3};
    const float gb = rsqrtf(2.0f * (float)M_PI * sigma_b * sigma_b);

    #pragma unroll
    for (int c = 0; c < 3; ++c) {
        const float Ia = Ias[c], Ib = Ibs[c];
        const float gap = Ib - Ia;
        const float I_min  = Ia + 0.5f * gap * (1.0f - ERF3OS2);
        const float I_diff = gap * ERF3OS2;
        const float add_c  = __logf(I_diff) - LOGN_F + (wv[3 + c] - lsew);
        const float ku = kus[c][n];
        const float tx = ku * I_diff + I_min;
        const float v  = 2.0f * (tx - Ia) / gap - 1.0f;
        const float ei = erfinvf(v);
        const float ei2 = ei * ei;
        const float G   = gap * gb * __expf(-ei2);
        const float lptx = -__logf(2.0f * WF * gap) + 0.5f * LOG2PI_F + ei2;
        const float B = -__logf(G) + lptx + add_c;

        const float txc = inv_sn2 * tx * L2E_F;
        const float gc  = 2.0f * inv_sn2 * G * L2E_F;
        const float zc  = (B - 0.5f * inv_sn2 * tx * tx - inv_sn2 * G * G) * L2E_F;
        tab[c * NMC + n] = make_float4(txc, gc, zc, 0.f);
    }

    if (n == 0) {
        const float lsn = __logf(sigma_n);
        hdr[0] = inv_sn2;
        hdr[1] = -2.f * lsn - 0.5f * LOG2PI_F - 0.5f * LOGPI_F;        // C_A (A_m = C_A + log y)
        hdr[2] = LOG2_F - LOGGAMMA15 - 4.f * lsn - 0.5f * LOG2PI_F;    // K_int
        hdr[3] = I1; hdr[4] = I2; hdr[5] = I3;
        hdr[6] = wv[0] - lsew; hdr[7] = wv[1] - lsew; hdr[8] = wv[2] - lsew;
        out[0] = 0.f;
    }
}

// ---------------- Kernel B: main loop ----------------
// Block = 256 threads = 4 waves. Lane (0..63) -> data point m; wave -> n-chunk of 256.
#define CHUNK 256

__global__ __launch_bounds__(256) void
main_kernel(const float* __restrict__ xg, const float* __restrict__ yg,
            const float4* __restrict__ tab, const float* __restrict__ hdr,
            float* __restrict__ out, int M) {
    const int lane = threadIdx.x & 63;
    const int wave = threadIdx.x >> 6;
    const int m = blockIdx.x * 64 + lane;
    const bool valid = (m < M);
    const float x = valid ? xg[m] : 0.5f;
    const float y = valid ? yg[m] : 0.5f;

    const float inv_sn2 = hdr[0];
    const float Cm = -(fmaf(0.5f * x, x, y * y)) * inv_sn2 * L2E_F;  // -(0.5x^2+y^2)/sn^2 * log2e

    float aa0 = 0.f, ab0 = 0.f;
    float aa1 = 0.f, ab1 = 0.f;
    float aa2 = 0.f, ab2 = 0.f;

    const int n0 = __builtin_amdgcn_readfirstlane(wave * CHUNK);
    #pragma unroll 8
    for (int i = 0; i < CHUNK; ++i) {
        const int n = n0 + i;
        {   // comp 0
            const float4 t = tab[0 * NMC + n];
            const float p = y * t.y;
            const float b = fmaf(x, t.x, t.z) + Cm;
            aa0 += EXP2(b + p);
            ab0 += EXP2(b - p);
        }
        {   // comp 1
            const float4 t = tab[1 * NMC + n];
            const float p = y * t.y;
            const float b = fmaf(x, t.x, t.z) + Cm;
            aa1 += EXP2(b + p);
            ab1 += EXP2(b - p);
        }
        {   // comp 2
            const float4 t = tab[2 * NMC + n];
            const float p = y * t.y;
            const float b = fmaf(x, t.x, t.z) + Cm;
            aa2 += EXP2(b + p);
            ab2 += EXP2(b - p);
        }
    }

    __shared__ float pac[4][3][64];
    pac[wave][0][lane] = aa0 - ab0;
    pac[wave][1][lane] = aa1 - ab1;
    pac[wave][2][lane] = aa2 - ab2;
    __syncthreads();

    if (wave == 0) {
        const float ly = __logf(y);
        const float A_m = hdr[1] + ly;
        const float base_int = hdr[2] + 2.f * ly - y * y * inv_sn2;
        float vals[6];
        #pragma unroll
        for (int c = 0; c < 3; ++c) {
            const float dxi = x - hdr[3 + c];
            vals[c] = hdr[6 + c] + base_int - 0.5f * dxi * dxi * inv_sn2;
        }
        #pragma unroll
        for (int c = 0; c < 3; ++c) {
            const float s = pac[0][c][lane] + pac[1][c][lane]
                          + pac[2][c][lane] + pac[3][c][lane];
            vals[3 + c] = A_m + __logf(fmaxf(s, 1e-38f));
        }
        float mm = vals[0];
        #pragma unroll
        for (int i = 1; i < 6; ++i) mm = fmaxf(mm, vals[i]);
        float se = 0.f;
        #pragma unroll
        for (int i = 0; i < 6; ++i) se += __expf(vals[i] - mm);
        const float log_mix = mm + __logf(se);
        float contrib = valid ? -log_mix : 0.f;
        #pragma unroll
        for (int off = 32; off > 0; off >>= 1) contrib += __shfl_down(contrib, off);
        if (lane == 0) atomicAdd(out, contrib);
    }
}

extern "C" void kernel_launch(void* const* d_in, const int* in_sizes, int n_in,
                              void* d_out, int out_size, void* d_ws, size_t ws_size,
                              hipStream_t stream) {
    const float* x    = (const float*)d_in[0];
    const float* y    = (const float*)d_in[1];
    const float* ku12 = (const float*)d_in[2];
    const float* ku23 = (const float*)d_in[3];
    const float* ku13 = (const float*)d_in[4];
    const float* sb   = (const float*)d_in[5];
    const float* sn   = (const float*)d_in[6];
    const float* I1   = (const float*)d_in[7];
    const float* I2   = (const float*)d_in[8];
    const float* I3   = (const float*)d_in[9];
    const float* w    = (const float*)d_in[10];
    const int M = in_sizes[0];

    float4* tab = (float4*)d_ws;
    float*  hdr = (float*)((char*)d_ws + 3 * NMC * sizeof(float4));
    float*  out = (float*)d_out;

    precompute_kernel<<<1, NMC, 0, stream>>>(ku12, ku23, ku13, sb, sn, I1, I2, I3, w,
                                             tab, hdr, out);
    const int blocks = (M + 63) / 64;
    main_kernel<<<blocks, 256, 0, stream>>>(x, y, tab, hdr, out, M);
}